// Round 2
// baseline (250.364 us; speedup 1.0000x reference)
//
#include <hip/hip_runtime.h>

#define T_LEN 1024
#define NS    128
#define BT    16
#define G     16
#define SEG   32         // time segments per sequence (power of 2)
#define SSH   5          // log2(SEG)
#define NB    256        // total batches

typedef __attribute__((ext_vector_type(8))) short short8;
typedef __attribute__((ext_vector_type(4))) short short4v;
typedef __attribute__((ext_vector_type(4))) float f32x4;

static __device__ __forceinline__ short f2bf(float f) {   // RNE (one-time uses)
    unsigned u = __builtin_bit_cast(unsigned, f);
    u = (u + 0x7fffu + ((u >> 16) & 1u)) >> 16;
    return (short)u;
}
static __device__ __forceinline__ float bf2f(short s) {
    unsigned u = ((unsigned)(unsigned short)s) << 16;
    return __builtin_bit_cast(float, u);
}
static __device__ __forceinline__ short f2bf_trunc(float f) {  // in-loop: 1 op
    return (short)(__builtin_bit_cast(unsigned, f) >> 16);
}

// Segmented CRF forward (rank-1 segment summaries, fwd units 0..30 / bwd 1..31,
// 62 units x 16 groups).  THIS ROUND: ONE WAVE per (unit,group) — each wave owns
// the full 128x128 matvec (E register-resident: 32 x short8 = 128 VGPRs, fine at
// 1 wave/SIMD).  The state exchange between the 4 quad row-chunks is wave-private
// LDS (4KB, SINGLE buffer: wave64 lockstep issues all ds_reads before ds_writes,
// so no WAR hazard) — ZERO s_barrier, only lgkmcnt(0).  992 blocks x 64 thr ≈
// 4 waves/CU, each self-paced; per-iter critical path is one wave's own chain.
// All layout formulas / normalizer / record semantics carried over verbatim from
// the verified 4-wave kernel (w -> unrolled j = 2w+mt, rows j*16+quad*4).
__global__ __launch_bounds__(64, 1) void crf_seg(
        const float* __restrict__ unary, const float* __restrict__ trans,
        const int* __restrict__ lengths,
        float* __restrict__ yv, float* __restrict__ zv,
        float* __restrict__ cfv, float* __restrict__ cbv) {
    __shared__ __align__(16) short Fs[BT * NS];   // 4KB bf16 state, XOR-swizzled

    const int tid = threadIdx.x;                  // 0..63 (one wave)
    const int g = blockIdx.x & (G - 1);
    const int u = blockIdx.x >> 4;                // 0..61
    const bool bwd = u >= (SEG - 1);
    const int s = bwd ? (u - (SEG - 2)) : u;      // fwd: 0..30 ; bwd: 1..31
    const int quad = tid >> 4, bcol = tid & 15;

    // ---- per-batch segment bounds (no shared arrays, no atomics) ----
    const int Lb = lengths[g * BT + bcol];
    const int tb = (s * Lb) >> SSH, te = ((s + 1) * Lb) >> SSH;
    const int nrec = te - tb - 1;                 // -1 => record happened at init
    int dlen = te - tb;
    #pragma unroll
    for (int m = 1; m < 16; m <<= 1) {            // max over the 16 batches
        int o = __shfl_xor(dlen, m, 64);
        dlen = o > dlen ? o : dlen;
    }
    const int iters = dlen;

    // ---- A-fragments: full E (fwd) or E^T (bwd), 8 m-tiles x 4 k-tiles ----
    short8 Ea[8][4];                              // 128 VGPRs
    #pragma unroll
    for (int j = 0; j < 8; ++j) {
        const int i = j * 16 + bcol;              // A's m-row
        #pragma unroll
        for (int kt = 0; kt < 4; ++kt) {
            short8 e;
            if (!bwd) {
                const float* tr = trans + (size_t)i * NS + kt * 32 + quad * 8;
                float4 x = *(const float4*)tr, y = *(const float4*)(tr + 4);
                e[0] = f2bf(__expf(x.x)); e[1] = f2bf(__expf(x.y));
                e[2] = f2bf(__expf(x.z)); e[3] = f2bf(__expf(x.w));
                e[4] = f2bf(__expf(y.x)); e[5] = f2bf(__expf(y.y));
                e[6] = f2bf(__expf(y.z)); e[7] = f2bf(__expf(y.w));
            } else {
                #pragma unroll
                for (int jj = 0; jj < 8; ++jj)
                    e[jj] = f2bf(__expf(trans[(size_t)(kt * 32 + quad * 8 + jj) * NS + i]));
            }
            Ea[j][kt] = e;
        }
    }

    // ---- init state into Fs + init-records for empty segments ----
    #pragma unroll
    for (int rep = 0; rep < 4; ++rep) {           // 4 reps x 64 lanes = 16x16 tile
        const int tv = rep * 64 + tid;
        const int sr = tv >> 4, sc = tv & 15;
        const int Ls = lengths[g * BT + sr];
        const int s_tb = (s * Ls) >> SSH, s_te = ((s + 1) * Ls) >> SSH;
        const float* ubase = unary + (size_t)(g * BT + sr) * T_LEN * NS + sc * 8;
        float v[8];
        if (!bwd) {
            #pragma unroll
            for (int k = 0; k < 8; ++k)
                v[k] = (s == 0) ? ((sc * 8 + k == 1) ? 1.f : 0.f) : 1.f;
        } else {
            int ti = s_te - 1; if (ti < 0) ti = 0;
            const float* up = ubase + (size_t)ti * NS;
            float4 ua = *(const float4*)up, ub4 = *(const float4*)(up + 4);
            float uu[8] = {ua.x, ua.y, ua.z, ua.w, ub4.x, ub4.y, ub4.z, ub4.w};
            #pragma unroll
            for (int k = 0; k < 8; ++k) {
                float vv = (s == SEG - 1) ? __expf(trans[2 * NS + sc * 8 + k]) : 1.f;
                v[k] = __expf(uu[k]) * vv;
            }
        }
        short8 z;
        #pragma unroll
        for (int k = 0; k < 8; ++k) z[k] = f2bf(v[k]);
        *(short8*)&Fs[sr * NS + ((sc ^ sr) << 3)] = z;

        if (s_te == s_tb) {   // empty segment: P = I, summary vector = init seed
            if (!bwd) {
                float* yp = yv + ((size_t)s * NB + g * BT + sr) * NS + sc * 8;
                #pragma unroll
                for (int k = 0; k < 8; ++k)
                    yp[k] = (s == 0) ? ((sc * 8 + k == 1) ? 1.f : 0.f) : 1.f;
                if (sc == 0) cfv[s * NB + g * BT + sr] = 0.f;
            } else {          // only middles can be empty; seed v = ones
                float* zp = zv + ((size_t)(s - 1) * NB + g * BT + sr) * NS + sc * 8;
                #pragma unroll
                for (int k = 0; k < 8; ++k) zp[k] = 1.f;
                if (sc == 0) cbv[(s - 1) * NB + g * BT + sr] = 0.f;
            }
        }
    }

    // ---- per-lane unary pointer: batch bcol, row slot j*16 + quad*4 ----
    const float* uptr = unary + (size_t)(g * BT + bcol) * T_LEN * NS + quad * 4;
    #define T_OFB(nn) ({ int _t = bwd ? (te - 2 - (nn)) : (tb + (nn)); \
                         _t = _t < 0 ? 0 : (_t > T_LEN - 1 ? T_LEN - 1 : _t); _t; })
    float4 pA[8], pB[8];                          // 2-deep prefetch (A even n, B odd)
    {
        int t = T_OFB(0);
        #pragma unroll
        for (int j = 0; j < 8; ++j) pA[j] = *(const float4*)(uptr + (size_t)t * NS + j * 16);
        t = T_OFB(1);
        #pragma unroll
        for (int j = 0; j < 8; ++j) pB[j] = *(const float4*)(uptr + (size_t)t * NS + j * 16);
    }

    // loop-invariant LDS offsets (same swizzle as verified kernel)
    int bfOff[4];
    #pragma unroll
    for (int kt = 0; kt < 4; ++kt) bfOff[kt] = bcol * NS + (((kt * 4 + quad) ^ bcol) << 3);
    const int s4Off = bcol * NS + (bcol << 3);    // logical chunk 0
    int fwo[8];
    #pragma unroll
    for (int j = 0; j < 8; ++j) {
        const int cj = 2 * j + (quad >> 1);       // chunk of rows j*16+quad*4..+3
        fwo[j] = bcol * NS + ((cj ^ bcol) << 3) + ((quad & 1) << 2);
    }

    asm volatile("s_waitcnt lgkmcnt(0)" ::: "memory");   // init staging visible (same wave)
    float C = 0.f;

    // One CRF step.  U: the 8 float4 unary regs for this n; consumed into exps,
    // then reloaded with t(n+2) (true 2-deep prefetch, statically indexed).
#define STEP(U) do {                                                              \
    short8 Bf0 = *(const short8*)&Fs[bfOff[0]];                                   \
    short8 Bf1 = *(const short8*)&Fs[bfOff[1]];                                   \
    short8 Bf2 = *(const short8*)&Fs[bfOff[2]];                                   \
    short8 Bf3 = *(const short8*)&Fs[bfOff[3]];                                   \
    short4v s4 = *(const short4v*)&Fs[s4Off];                                     \
    float e_[8][4];                                                               \
    _Pragma("unroll")                                                             \
    for (int j = 0; j < 8; ++j) {                                                 \
        e_[j][0] = __expf(U[j].x); e_[j][1] = __expf(U[j].y);                     \
        e_[j][2] = __expf(U[j].z); e_[j][3] = __expf(U[j].w);                     \
    }                                                                             \
    { int t = T_OFB(n + 2);                                                       \
      _Pragma("unroll")                                                           \
      for (int j = 0; j < 8; ++j)                                                 \
          U[j] = *(const float4*)(uptr + (size_t)t * NS + j * 16); }              \
    f32x4 acc[8];                                                                 \
    _Pragma("unroll")                                                             \
    for (int j = 0; j < 8; ++j) acc[j] = (f32x4){0.f, 0.f, 0.f, 0.f};             \
    _Pragma("unroll")                                                             \
    for (int j = 0; j < 8; ++j) acc[j] = __builtin_amdgcn_mfma_f32_16x16x32_bf16(Ea[j][0], Bf0, acc[j], 0, 0, 0); \
    _Pragma("unroll")                                                             \
    for (int j = 0; j < 8; ++j) acc[j] = __builtin_amdgcn_mfma_f32_16x16x32_bf16(Ea[j][1], Bf1, acc[j], 0, 0, 0); \
    _Pragma("unroll")                                                             \
    for (int j = 0; j < 8; ++j) acc[j] = __builtin_amdgcn_mfma_f32_16x16x32_bf16(Ea[j][2], Bf2, acc[j], 0, 0, 0); \
    _Pragma("unroll")                                                             \
    for (int j = 0; j < 8; ++j) acc[j] = __builtin_amdgcn_mfma_f32_16x16x32_bf16(Ea[j][3], Bf3, acc[j], 0, 0, 0); \
    float sv = (bf2f(s4[0]) + bf2f(s4[1])) + (bf2f(s4[2]) + bf2f(s4[3]));         \
    float rs = __fdividef(1.f, sv);                                               \
    float logs = __logf(sv);                                                      \
    float fn[8][4];                                                               \
    _Pragma("unroll")                                                             \
    for (int j = 0; j < 8; ++j) {                                                 \
        fn[j][0] = acc[j][0] * e_[j][0] * rs; fn[j][1] = acc[j][1] * e_[j][1] * rs; \
        fn[j][2] = acc[j][2] * e_[j][2] * rs; fn[j][3] = acc[j][3] * e_[j][3] * rs; \
    }                                                                             \
    if (n == nrec) {                                                              \
        if (!bwd) {   /* record normalized post-step state + C_after */           \
            float* yp = yv + ((size_t)s * NB + g * BT + bcol) * NS;               \
            _Pragma("unroll")                                                     \
            for (int j = 0; j < 8; ++j)                                           \
                *(float4*)(yp + j * 16 + quad * 4) = (float4){fn[j][0], fn[j][1], fn[j][2], fn[j][3]}; \
            if (tid < BT) cfv[s * NB + g * BT + tid] = C + logs;                  \
        } else {      /* record RAW acc = E^T q (pre-eu) + C_before */            \
            float* zp = zv + ((size_t)(s - 1) * NB + g * BT + bcol) * NS;         \
            _Pragma("unroll")                                                     \
            for (int j = 0; j < 8; ++j)                                           \
                *(float4*)(zp + j * 16 + quad * 4) = (float4){acc[j][0], acc[j][1], acc[j][2], acc[j][3]}; \
            if (tid < BT) cbv[(s - 1) * NB + g * BT + tid] = C;                   \
        }                                                                         \
    }                                                                             \
    C += logs;                                                                    \
    _Pragma("unroll")                                                             \
    for (int j = 0; j < 8; ++j) {                                                 \
        short4v p;                                                                \
        p[0] = f2bf_trunc(fn[j][0]); p[1] = f2bf_trunc(fn[j][1]);                 \
        p[2] = f2bf_trunc(fn[j][2]); p[3] = f2bf_trunc(fn[j][3]);                 \
        *(short4v*)&Fs[fwo[j]] = p;                                               \
    }                                                                             \
    /* same-wave RAW on LDS: only lgkmcnt needed — NO barrier */                  \
    asm volatile("s_waitcnt lgkmcnt(0)" ::: "memory");                            \
} while (0)

    for (int n = 0; n < iters; ) {
        STEP(pA); ++n;
        if (n >= iters) break;
        STEP(pB); ++n;
    }
#undef STEP
#undef T_OFB
}

// out = Cf_0 + sum_{s=1..S-1} Cb_s + sum_{s=1..S-1} log(Z_s . Y_{s-1})
//       - sum_{s=1..S-2} log sum(Y_s)
__global__ __launch_bounds__(64) void crf_combine(
        const float* __restrict__ yv, const float* __restrict__ zv,
        const float* __restrict__ cfv, const float* __restrict__ cbv,
        float* __restrict__ out) {
    const int b = blockIdx.x, lane = threadIdx.x;
    float acc = cfv[b];
    for (int s = 1; s <= SEG - 1; ++s) acc += cbv[(s - 1) * NB + b];
    float lg = 0.f;
    for (int s = 1; s <= SEG - 1; ++s) {
        const float* Z = zv + ((size_t)(s - 1) * NB + b) * NS;
        const float* Y = yv + ((size_t)(s - 1) * NB + b) * NS;
        float d = Z[lane] * Y[lane] + Z[lane + 64] * Y[lane + 64];
        #pragma unroll
        for (int off = 1; off < 64; off <<= 1) d += __shfl_xor(d, off, 64);
        lg += __logf(d);
    }
    for (int s = 1; s <= SEG - 2; ++s) {
        const float* Y = yv + ((size_t)s * NB + b) * NS;
        float t = Y[lane] + Y[lane + 64];
        #pragma unroll
        for (int off = 1; off < 64; off <<= 1) t += __shfl_xor(t, off, 64);
        lg -= __logf(t);
    }
    if (lane == 0) out[b] = acc + lg;
}

extern "C" void kernel_launch(void* const* d_in, const int* in_sizes, int n_in,
                              void* d_out, int out_size, void* d_ws, size_t ws_size,
                              hipStream_t stream) {
    const float* unary   = (const float*)d_in[0];
    const float* trans   = (const float*)d_in[1];
    const int*   lengths = (const int*)d_in[2];
    float* out = (float*)d_out;

    float* yv  = (float*)d_ws;                          // [S-1][NB][NS]
    float* zv  = yv + (size_t)(SEG - 1) * NB * NS;      // [S-1][NB][NS]
    float* cfv = zv + (size_t)(SEG - 1) * NB * NS;      // [S-1][NB]
    float* cbv = cfv + (size_t)(SEG - 1) * NB;          // [S-1][NB]

    crf_seg<<<dim3(2 * (SEG - 1) * G), dim3(64), 0, stream>>>(
        unary, trans, lengths, yv, zv, cfv, cbv);
    crf_combine<<<dim3(NB), dim3(64), 0, stream>>>(yv, zv, cfv, cbv, out);
}

// Round 3
// 245.629 us; speedup vs baseline: 1.0193x; 1.0193x over previous
//
#include <hip/hip_runtime.h>

#define T_LEN 1024
#define NS    128
#define BT    16
#define G     16
#define SEG   64         // time segments per sequence (power of 2)
#define SSH   6          // log2(SEG)
#define NB    256        // total batches

typedef __attribute__((ext_vector_type(8))) short short8;
typedef __attribute__((ext_vector_type(4))) short short4v;
typedef __attribute__((ext_vector_type(4))) float f32x4;

static __device__ __forceinline__ short f2bf(float f) {   // RNE (one-time uses)
    unsigned u = __builtin_bit_cast(unsigned, f);
    u = (u + 0x7fffu + ((u >> 16) & 1u)) >> 16;
    return (short)u;
}
static __device__ __forceinline__ float bf2f(short s) {
    unsigned u = ((unsigned)(unsigned short)s) << 16;
    return __builtin_bit_cast(float, u);
}
static __device__ __forceinline__ short f2bf_trunc(float f) {  // in-loop: 1 op
    return (short)(__builtin_bit_cast(unsigned, f) >> 16);
}

// Segmented CRF forward (rank-1 segment summaries, fwd units 0..S-2 / bwd 1..S-1,
// 2*(S-1) units x 16 groups, ONE WAVE each).  R2 showed pure latency regime (all
// pipes <20%, ~6.6k cy/iter): wall = iters x per-step chain.  THIS ROUND:
// SEG 32->64 halves sequential depth (iters ~32->~16).  To keep ALL 2016 waves
// co-resident (2 waves/SIMD, combined VGPR+AGPR <= 256): single-buffer unary
// prefetch U (issued post-MFMA, consumed post-MFMA next iter -> full-iter slack)
// and exp(U) fused per-j with the reload (e_ peak 4 regs).  Forced via
// __launch_bounds__(64, 2).  Layout/normalizer/record semantics verbatim from
// the R2-verified kernel.
__global__ __launch_bounds__(64, 2) void crf_seg(
        const float* __restrict__ unary, const float* __restrict__ trans,
        const int* __restrict__ lengths,
        float* __restrict__ yv, float* __restrict__ zv,
        float* __restrict__ cfv, float* __restrict__ cbv) {
    __shared__ __align__(16) short Fs[BT * NS];   // 4KB bf16 state, XOR-swizzled

    const int tid = threadIdx.x;                  // 0..63 (one wave)
    const int g = blockIdx.x & (G - 1);
    const int u = blockIdx.x >> 4;                // 0..2*(SEG-1)-1
    const bool bwd = u >= (SEG - 1);
    const int s = bwd ? (u - (SEG - 2)) : u;      // fwd: 0..S-2 ; bwd: 1..S-1
    const int quad = tid >> 4, bcol = tid & 15;

    // ---- per-batch segment bounds ----
    const int Lb = lengths[g * BT + bcol];
    const int tb = (s * Lb) >> SSH, te = ((s + 1) * Lb) >> SSH;
    const int nrec = te - tb - 1;                 // -1 => record happened at init
    int dlen = te - tb;
    #pragma unroll
    for (int m = 1; m < 16; m <<= 1) {            // max over the 16 batches
        int o = __shfl_xor(dlen, m, 64);
        dlen = o > dlen ? o : dlen;
    }
    const int iters = dlen;

    // ---- A-fragments: full E (fwd) or E^T (bwd), 8 m-tiles x 4 k-tiles ----
    short8 Ea[8][4];                              // 128 regs (VGPR/AGPR unified)
    #pragma unroll
    for (int j = 0; j < 8; ++j) {
        const int i = j * 16 + bcol;              // A's m-row
        #pragma unroll
        for (int kt = 0; kt < 4; ++kt) {
            short8 e;
            if (!bwd) {
                const float* tr = trans + (size_t)i * NS + kt * 32 + quad * 8;
                float4 x = *(const float4*)tr, y = *(const float4*)(tr + 4);
                e[0] = f2bf(__expf(x.x)); e[1] = f2bf(__expf(x.y));
                e[2] = f2bf(__expf(x.z)); e[3] = f2bf(__expf(x.w));
                e[4] = f2bf(__expf(y.x)); e[5] = f2bf(__expf(y.y));
                e[6] = f2bf(__expf(y.z)); e[7] = f2bf(__expf(y.w));
            } else {
                #pragma unroll
                for (int jj = 0; jj < 8; ++jj)
                    e[jj] = f2bf(__expf(trans[(size_t)(kt * 32 + quad * 8 + jj) * NS + i]));
            }
            Ea[j][kt] = e;
        }
    }

    // ---- init state into Fs + init-records for empty segments ----
    #pragma unroll
    for (int rep = 0; rep < 4; ++rep) {           // 4 reps x 64 lanes = 16x16 tile
        const int tv = rep * 64 + tid;
        const int sr = tv >> 4, sc = tv & 15;
        const int Ls = lengths[g * BT + sr];
        const int s_tb = (s * Ls) >> SSH, s_te = ((s + 1) * Ls) >> SSH;
        const float* ubase = unary + (size_t)(g * BT + sr) * T_LEN * NS + sc * 8;
        float v[8];
        if (!bwd) {
            #pragma unroll
            for (int k = 0; k < 8; ++k)
                v[k] = (s == 0) ? ((sc * 8 + k == 1) ? 1.f : 0.f) : 1.f;
        } else {
            int ti = s_te - 1; if (ti < 0) ti = 0;
            const float* up = ubase + (size_t)ti * NS;
            float4 ua = *(const float4*)up, ub4 = *(const float4*)(up + 4);
            float uu[8] = {ua.x, ua.y, ua.z, ua.w, ub4.x, ub4.y, ub4.z, ub4.w};
            #pragma unroll
            for (int k = 0; k < 8; ++k) {
                float vv = (s == SEG - 1) ? __expf(trans[2 * NS + sc * 8 + k]) : 1.f;
                v[k] = __expf(uu[k]) * vv;
            }
        }
        short8 z;
        #pragma unroll
        for (int k = 0; k < 8; ++k) z[k] = f2bf(v[k]);
        *(short8*)&Fs[sr * NS + ((sc ^ sr) << 3)] = z;

        if (s_te == s_tb) {   // empty segment: P = I, summary vector = init seed
            if (!bwd) {
                float* yp = yv + ((size_t)s * NB + g * BT + sr) * NS + sc * 8;
                #pragma unroll
                for (int k = 0; k < 8; ++k)
                    yp[k] = (s == 0) ? ((sc * 8 + k == 1) ? 1.f : 0.f) : 1.f;
                if (sc == 0) cfv[s * NB + g * BT + sr] = 0.f;
            } else {          // only middles can be empty; seed v = ones
                float* zp = zv + ((size_t)(s - 1) * NB + g * BT + sr) * NS + sc * 8;
                #pragma unroll
                for (int k = 0; k < 8; ++k) zp[k] = 1.f;
                if (sc == 0) cbv[(s - 1) * NB + g * BT + sr] = 0.f;
            }
        }
    }

    // ---- per-lane unary pointer: batch bcol, row slot j*16 + quad*4 ----
    const float* uptr = unary + (size_t)(g * BT + bcol) * T_LEN * NS + quad * 4;
    #define T_OFB(nn) ({ int _t = bwd ? (te - 2 - (nn)) : (tb + (nn)); \
                         _t = _t < 0 ? 0 : (_t > T_LEN - 1 ? T_LEN - 1 : _t); _t; })
    float4 U[8];                                  // single-buffer prefetch
    {
        int t = T_OFB(0);
        #pragma unroll
        for (int j = 0; j < 8; ++j) U[j] = *(const float4*)(uptr + (size_t)t * NS + j * 16);
    }

    // loop-invariant LDS offsets (verbatim swizzle)
    int bfOff[4];
    #pragma unroll
    for (int kt = 0; kt < 4; ++kt) bfOff[kt] = bcol * NS + (((kt * 4 + quad) ^ bcol) << 3);
    const int s4Off = bcol * NS + (bcol << 3);    // logical chunk 0
    int fwo[8];
    #pragma unroll
    for (int j = 0; j < 8; ++j) {
        const int cj = 2 * j + (quad >> 1);       // chunk of rows j*16+quad*4..+3
        fwo[j] = bcol * NS + ((cj ^ bcol) << 3) + ((quad & 1) << 2);
    }

    asm volatile("s_waitcnt lgkmcnt(0)" ::: "memory");   // init staging visible (same wave)
    float C = 0.f;

    for (int n = 0; n < iters; ++n) {
        // state + normalizer proxy from LDS
        short8 Bf0 = *(const short8*)&Fs[bfOff[0]];
        short8 Bf1 = *(const short8*)&Fs[bfOff[1]];
        short8 Bf2 = *(const short8*)&Fs[bfOff[2]];
        short8 Bf3 = *(const short8*)&Fs[bfOff[3]];
        short4v s4 = *(const short4v*)&Fs[s4Off];

        // normalizer chain (overlaps MFMA issue; only needs s4)
        float sv = (bf2f(s4[0]) + bf2f(s4[1])) + (bf2f(s4[2]) + bf2f(s4[3]));
        float rs = __fdividef(1.f, sv);
        float logs = __logf(sv);

        // matvec: 8 independent 4-deep MFMA chains
        f32x4 acc[8];
        #pragma unroll
        for (int j = 0; j < 8; ++j) acc[j] = (f32x4){0.f, 0.f, 0.f, 0.f};
        #pragma unroll
        for (int j = 0; j < 8; ++j) acc[j] = __builtin_amdgcn_mfma_f32_16x16x32_bf16(Ea[j][0], Bf0, acc[j], 0, 0, 0);
        #pragma unroll
        for (int j = 0; j < 8; ++j) acc[j] = __builtin_amdgcn_mfma_f32_16x16x32_bf16(Ea[j][1], Bf1, acc[j], 0, 0, 0);
        #pragma unroll
        for (int j = 0; j < 8; ++j) acc[j] = __builtin_amdgcn_mfma_f32_16x16x32_bf16(Ea[j][2], Bf2, acc[j], 0, 0, 0);
        #pragma unroll
        for (int j = 0; j < 8; ++j) acc[j] = __builtin_amdgcn_mfma_f32_16x16x32_bf16(Ea[j][3], Bf3, acc[j], 0, 0, 0);

        if (bwd && n == nrec) {   // record RAW acc = E^T q (pre-eu) + C_before
            float* zp = zv + ((size_t)(s - 1) * NB + g * BT + bcol) * NS;
            #pragma unroll
            for (int j = 0; j < 8; ++j)
                *(float4*)(zp + j * 16 + quad * 4) = (float4){acc[j][0], acc[j][1], acc[j][2], acc[j][3]};
            if (tid < BT) cbv[(s - 1) * NB + g * BT + tid] = C;
        }

        // scale in place: acc[j] *= exp(U[j]) * rs, then reload U[j] for n+1.
        // exp is per-j pipelined (e4 peak 4 regs); reload consumed at this same
        // phase next iter -> full-iteration slack for the global loads.
        {
            int t = T_OFB(n + 1);
            #pragma unroll
            for (int j = 0; j < 8; ++j) {
                float e0 = __expf(U[j].x), e1 = __expf(U[j].y);
                float e2 = __expf(U[j].z), e3 = __expf(U[j].w);
                acc[j][0] *= e0 * rs; acc[j][1] *= e1 * rs;
                acc[j][2] *= e2 * rs; acc[j][3] *= e3 * rs;
                U[j] = *(const float4*)(uptr + (size_t)t * NS + j * 16);
            }
        }

        if (!bwd && n == nrec) {  // record normalized post-step state + C_after
            float* yp = yv + ((size_t)s * NB + g * BT + bcol) * NS;
            #pragma unroll
            for (int j = 0; j < 8; ++j)
                *(float4*)(yp + j * 16 + quad * 4) = (float4){acc[j][0], acc[j][1], acc[j][2], acc[j][3]};
            if (tid < BT) cfv[s * NB + g * BT + tid] = C + logs;
        }
        C += logs;

        #pragma unroll
        for (int j = 0; j < 8; ++j) {
            short4v p;
            p[0] = f2bf_trunc(acc[j][0]); p[1] = f2bf_trunc(acc[j][1]);
            p[2] = f2bf_trunc(acc[j][2]); p[3] = f2bf_trunc(acc[j][3]);
            *(short4v*)&Fs[fwo[j]] = p;
        }
        // same-wave RAW on LDS: only lgkmcnt needed — NO barrier
        asm volatile("s_waitcnt lgkmcnt(0)" ::: "memory");
    }
#undef T_OFB
}

// out = Cf_0 + sum_{s=1..S-1} Cb_s + sum_{s=1..S-1} log(Z_s . Y_{s-1})
//       - sum_{s=1..S-2} log sum(Y_s)
// 4 waves split the s-range (strided); deterministic LDS combine.
__global__ __launch_bounds__(256) void crf_combine(
        const float* __restrict__ yv, const float* __restrict__ zv,
        const float* __restrict__ cfv, const float* __restrict__ cbv,
        float* __restrict__ out) {
    __shared__ float part[4];
    const int b = blockIdx.x, tid = threadIdx.x;
    const int w = tid >> 6, lane = tid & 63;
    float lg = 0.f;
    for (int s = 1 + w; s <= SEG - 1; s += 4) lg += cbv[(s - 1) * NB + b];
    for (int s = 1 + w; s <= SEG - 1; s += 4) {
        const float* Z = zv + ((size_t)(s - 1) * NB + b) * NS;
        const float* Y = yv + ((size_t)(s - 1) * NB + b) * NS;
        float d = Z[lane] * Y[lane] + Z[lane + 64] * Y[lane + 64];
        #pragma unroll
        for (int off = 1; off < 64; off <<= 1) d += __shfl_xor(d, off, 64);
        lg += __logf(d);
    }
    for (int s = 1 + w; s <= SEG - 2; s += 4) {
        const float* Y = yv + ((size_t)s * NB + b) * NS;
        float t = Y[lane] + Y[lane + 64];
        #pragma unroll
        for (int off = 1; off < 64; off <<= 1) t += __shfl_xor(t, off, 64);
        lg -= __logf(t);
    }
    if (lane == 0) part[w] = lg;
    __syncthreads();
    if (tid == 0) out[b] = cfv[b] + ((part[0] + part[1]) + (part[2] + part[3]));
}

extern "C" void kernel_launch(void* const* d_in, const int* in_sizes, int n_in,
                              void* d_out, int out_size, void* d_ws, size_t ws_size,
                              hipStream_t stream) {
    const float* unary   = (const float*)d_in[0];
    const float* trans   = (const float*)d_in[1];
    const int*   lengths = (const int*)d_in[2];
    float* out = (float*)d_out;

    float* yv  = (float*)d_ws;                          // [S-1][NB][NS]
    float* zv  = yv + (size_t)(SEG - 1) * NB * NS;      // [S-1][NB][NS]
    float* cfv = zv + (size_t)(SEG - 1) * NB * NS;      // [S-1][NB]
    float* cbv = cfv + (size_t)(SEG - 1) * NB;          // [S-1][NB]

    crf_seg<<<dim3(2 * (SEG - 1) * G), dim3(64), 0, stream>>>(
        unary, trans, lengths, yv, zv, cfv, cbv);
    crf_combine<<<dim3(NB), dim3(256), 0, stream>>>(yv, zv, cfv, cbv, out);
}

// Round 4
// 243.110 us; speedup vs baseline: 1.0298x; 1.0104x over previous
//
#include <hip/hip_runtime.h>

#define T_LEN 1024
#define NS    128
#define BT    16
#define G     16
#define SEG   64         // time segments per sequence (power of 2)
#define SSH   6          // log2(SEG)
#define NB    256        // total batches

typedef __attribute__((ext_vector_type(8))) short short8;
typedef __attribute__((ext_vector_type(4))) short short4v;
typedef __attribute__((ext_vector_type(4))) float f32x4;

static __device__ __forceinline__ short f2bf(float f) {   // RNE (one-time uses)
    unsigned u = __builtin_bit_cast(unsigned, f);
    u = (u + 0x7fffu + ((u >> 16) & 1u)) >> 16;
    return (short)u;
}
static __device__ __forceinline__ float bf2f(short s) {
    unsigned u = ((unsigned)(unsigned short)s) << 16;
    return __builtin_bit_cast(float, u);
}
static __device__ __forceinline__ short f2bf_trunc(float f) {  // in-loop: 1 op
    return (short)(__builtin_bit_cast(unsigned, f) >> 16);
}

// Segmented CRF forward (rank-1 segment summaries, fwd units 0..S-2 / bwd 1..S-1,
// 2*(S-1) units x 16 groups, ONE WAVE each).  R1-R3 established the wall is the
// MEMORY SYSTEM at ~1.35 TB/s (21% of peak): every prior variant loaded unary as
// 16 batches x 64B per instruction (512KB stride) -> ~32k interleaved 64B streams
// -> DRAM page-activation bound.  THIS ROUND: unary staged via
// global_load_lds with CONTIGUOUS 512B-per-row requests (one instr = 2 batches x
// full 128-float row, 32 lanes each), linear LDS dest + pre-swizzled global
// source (chunk c of batch b -> slot c^(b&7)); reader applies the same XOR ->
// bank-optimal ds_read_b128 (8 chunks/bank-column).  Single 8KB Ul buffer:
// vmcnt(0) before consume, lgkmcnt(0) before re-issue.  Row index t per
// TARGET batch (shfl'd bounds), not per lane.  Everything else verbatim R3.
__global__ __launch_bounds__(64, 2) void crf_seg(
        const float* __restrict__ unary, const float* __restrict__ trans,
        const int* __restrict__ lengths,
        float* __restrict__ yv, float* __restrict__ zv,
        float* __restrict__ cfv, float* __restrict__ cbv) {
    __shared__ __align__(16) short Fs[BT * NS];   // 4KB bf16 state, XOR-swizzled
    __shared__ __align__(16) float Ul[BT * NS];   // 8KB unary tile (swizzled chunks)

    const int tid = threadIdx.x;                  // 0..63 (one wave)
    const int g = blockIdx.x & (G - 1);
    const int u = blockIdx.x >> 4;                // 0..2*(SEG-1)-1
    const bool bwd = u >= (SEG - 1);
    const int s = bwd ? (u - (SEG - 2)) : u;      // fwd: 0..S-2 ; bwd: 1..S-1
    const int quad = tid >> 4, bcol = tid & 15;

    // ---- per-batch segment bounds ----
    const int Lb = lengths[g * BT + bcol];
    const int tb = (s * Lb) >> SSH, te = ((s + 1) * Lb) >> SSH;
    const int nrec = te - tb - 1;                 // -1 => record happened at init
    int dlen = te - tb;
    #pragma unroll
    for (int m = 1; m < 16; m <<= 1) {            // max over the 16 batches
        int o = __shfl_xor(dlen, m, 64);
        dlen = o > dlen ? o : dlen;
    }
    const int iters = dlen;

    // ---- A-fragments: full E (fwd) or E^T (bwd), 8 m-tiles x 4 k-tiles ----
    short8 Ea[8][4];                              // 128 regs (VGPR/AGPR unified)
    #pragma unroll
    for (int j = 0; j < 8; ++j) {
        const int i = j * 16 + bcol;              // A's m-row
        #pragma unroll
        for (int kt = 0; kt < 4; ++kt) {
            short8 e;
            if (!bwd) {
                const float* tr = trans + (size_t)i * NS + kt * 32 + quad * 8;
                float4 x = *(const float4*)tr, y = *(const float4*)(tr + 4);
                e[0] = f2bf(__expf(x.x)); e[1] = f2bf(__expf(x.y));
                e[2] = f2bf(__expf(x.z)); e[3] = f2bf(__expf(x.w));
                e[4] = f2bf(__expf(y.x)); e[5] = f2bf(__expf(y.y));
                e[6] = f2bf(__expf(y.z)); e[7] = f2bf(__expf(y.w));
            } else {
                #pragma unroll
                for (int jj = 0; jj < 8; ++jj)
                    e[jj] = f2bf(__expf(trans[(size_t)(kt * 32 + quad * 8 + jj) * NS + i]));
            }
            Ea[j][kt] = e;
        }
    }

    // ---- init state into Fs + init-records for empty segments ----
    #pragma unroll
    for (int rep = 0; rep < 4; ++rep) {           // 4 reps x 64 lanes = 16x16 tile
        const int tv = rep * 64 + tid;
        const int sr = tv >> 4, sc = tv & 15;
        const int Ls = lengths[g * BT + sr];
        const int s_tb = (s * Ls) >> SSH, s_te = ((s + 1) * Ls) >> SSH;
        const float* ubase = unary + (size_t)(g * BT + sr) * T_LEN * NS + sc * 8;
        float v[8];
        if (!bwd) {
            #pragma unroll
            for (int k = 0; k < 8; ++k)
                v[k] = (s == 0) ? ((sc * 8 + k == 1) ? 1.f : 0.f) : 1.f;
        } else {
            int ti = s_te - 1; if (ti < 0) ti = 0;
            const float* up = ubase + (size_t)ti * NS;
            float4 ua = *(const float4*)up, ub4 = *(const float4*)(up + 4);
            float uu[8] = {ua.x, ua.y, ua.z, ua.w, ub4.x, ub4.y, ub4.z, ub4.w};
            #pragma unroll
            for (int k = 0; k < 8; ++k) {
                float vv = (s == SEG - 1) ? __expf(trans[2 * NS + sc * 8 + k]) : 1.f;
                v[k] = __expf(uu[k]) * vv;
            }
        }
        short8 z;
        #pragma unroll
        for (int k = 0; k < 8; ++k) z[k] = f2bf(v[k]);
        *(short8*)&Fs[sr * NS + ((sc ^ sr) << 3)] = z;

        if (s_te == s_tb) {   // empty segment: P = I, summary vector = init seed
            if (!bwd) {
                float* yp = yv + ((size_t)s * NB + g * BT + sr) * NS + sc * 8;
                #pragma unroll
                for (int k = 0; k < 8; ++k)
                    yp[k] = (s == 0) ? ((sc * 8 + k == 1) ? 1.f : 0.f) : 1.f;
                if (sc == 0) cfv[s * NB + g * BT + sr] = 0.f;
            } else {          // only middles can be empty; seed v = ones
                float* zp = zv + ((size_t)(s - 1) * NB + g * BT + sr) * NS + sc * 8;
                #pragma unroll
                for (int k = 0; k < 8; ++k) zp[k] = 1.f;
                if (sc == 0) cbv[(s - 1) * NB + g * BT + sr] = 0.f;
            }
        }
    }

    // ---- staging geometry: instr k loads batches {2k, 2k+1}, 512B/row each ----
    const int l5 = tid >> 5, l31 = tid & 31;
    const float* gK[8];                           // per-lane pre-swizzled src base
    int baseK[8];                                 // per-instr start t (target batch!)
    #pragma unroll
    for (int k = 0; k < 8; ++k) {
        const int b = 2 * k + l5;
        gK[k] = unary + (size_t)(g * BT + b) * T_LEN * NS + ((l31 ^ (b & 7)) << 2);
        const int LbK = __shfl(Lb, b, 64);        // lane b holds batch b's length
        const int tbK = (s * LbK) >> SSH, teK = ((s + 1) * LbK) >> SSH;
        baseK[k] = bwd ? (teK - 2) : tbK;
    }
    #define T_OFK(k, nn) ({ int _t = bwd ? (baseK[k] - (nn)) : (baseK[k] + (nn)); \
                            _t = _t < 0 ? 0 : (_t > T_LEN - 1 ? T_LEN - 1 : _t); _t; })

    // prologue: DMA tile t(0) into Ul (linear dest, 2 rows x 512B per instr)
    #pragma unroll
    for (int k = 0; k < 8; ++k) {
        int t = T_OFK(k, 0);
        __builtin_amdgcn_global_load_lds(
            (const __attribute__((address_space(1))) void*)(gK[k] + (size_t)t * NS),
            (__attribute__((address_space(3))) void*)((char*)Ul + k * 1024),
            16, 0, 0);
    }

    // loop-invariant LDS offsets
    int bfOff[4];
    #pragma unroll
    for (int kt = 0; kt < 4; ++kt) bfOff[kt] = bcol * NS + (((kt * 4 + quad) ^ bcol) << 3);
    const int s4Off = bcol * NS + (bcol << 3);    // logical chunk 0
    int fwo[8];
    #pragma unroll
    for (int j = 0; j < 8; ++j) {
        const int cj = 2 * j + (quad >> 1);       // chunk of rows j*16+quad*4..+3
        fwo[j] = bcol * NS + ((cj ^ bcol) << 3) + ((quad & 1) << 2);
    }
    int uOff[8];                                  // float idx: batch bcol, chunk j*4+quad
    #pragma unroll
    for (int j = 0; j < 8; ++j)
        uOff[j] = bcol * NS + (((j * 4 + quad) ^ (bcol & 7)) << 2);

    asm volatile("s_waitcnt lgkmcnt(0)" ::: "memory");   // init staging visible (same wave)
    float C = 0.f;

    for (int n = 0; n < iters; ++n) {
        // state + normalizer proxy from LDS
        short8 Bf0 = *(const short8*)&Fs[bfOff[0]];
        short8 Bf1 = *(const short8*)&Fs[bfOff[1]];
        short8 Bf2 = *(const short8*)&Fs[bfOff[2]];
        short8 Bf3 = *(const short8*)&Fs[bfOff[3]];
        short4v s4 = *(const short4v*)&Fs[s4Off];

        // normalizer chain (overlaps MFMA issue; only needs s4)
        float sv = (bf2f(s4[0]) + bf2f(s4[1])) + (bf2f(s4[2]) + bf2f(s4[3]));
        float rs = __fdividef(1.f, sv);
        float logs = __logf(sv);

        // matvec: 8 independent 4-deep MFMA chains
        f32x4 acc[8];
        #pragma unroll
        for (int j = 0; j < 8; ++j) acc[j] = (f32x4){0.f, 0.f, 0.f, 0.f};
        #pragma unroll
        for (int j = 0; j < 8; ++j) acc[j] = __builtin_amdgcn_mfma_f32_16x16x32_bf16(Ea[j][0], Bf0, acc[j], 0, 0, 0);
        #pragma unroll
        for (int j = 0; j < 8; ++j) acc[j] = __builtin_amdgcn_mfma_f32_16x16x32_bf16(Ea[j][1], Bf1, acc[j], 0, 0, 0);
        #pragma unroll
        for (int j = 0; j < 8; ++j) acc[j] = __builtin_amdgcn_mfma_f32_16x16x32_bf16(Ea[j][2], Bf2, acc[j], 0, 0, 0);
        #pragma unroll
        for (int j = 0; j < 8; ++j) acc[j] = __builtin_amdgcn_mfma_f32_16x16x32_bf16(Ea[j][3], Bf3, acc[j], 0, 0, 0);

        if (bwd && n == nrec) {   // record RAW acc = E^T q (pre-eu) + C_before
            float* zp = zv + ((size_t)(s - 1) * NB + g * BT + bcol) * NS;
            #pragma unroll
            for (int j = 0; j < 8; ++j)
                *(float4*)(zp + j * 16 + quad * 4) = (float4){acc[j][0], acc[j][1], acc[j][2], acc[j][3]};
            if (tid < BT) cbv[(s - 1) * NB + g * BT + tid] = C;
        }

        // U tile landed? (only U-DMAs + rare record stores are in vmcnt)
        asm volatile("s_waitcnt vmcnt(0)" ::: "memory");
        #pragma unroll
        for (int j = 0; j < 8; ++j) {
            float4 uv = *(const float4*)&Ul[uOff[j]];
            float e0 = __expf(uv.x), e1 = __expf(uv.y);
            float e2 = __expf(uv.z), e3 = __expf(uv.w);
            acc[j][0] *= e0 * rs; acc[j][1] *= e1 * rs;
            acc[j][2] *= e2 * rs; acc[j][3] *= e3 * rs;
        }

        if (!bwd && n == nrec) {  // record normalized post-step state + C_after
            float* yp = yv + ((size_t)s * NB + g * BT + bcol) * NS;
            #pragma unroll
            for (int j = 0; j < 8; ++j)
                *(float4*)(yp + j * 16 + quad * 4) = (float4){acc[j][0], acc[j][1], acc[j][2], acc[j][3]};
            if (tid < BT) cfv[s * NB + g * BT + tid] = C + logs;
        }
        C += logs;

        // Ul reads retired (exp consumed them; pin with lgkm) -> re-issue DMA
        asm volatile("s_waitcnt lgkmcnt(0)" ::: "memory");
        if (n + 1 < iters) {
            #pragma unroll
            for (int k = 0; k < 8; ++k) {
                int t = T_OFK(k, n + 1);
                __builtin_amdgcn_global_load_lds(
                    (const __attribute__((address_space(1))) void*)(gK[k] + (size_t)t * NS),
                    (__attribute__((address_space(3))) void*)((char*)Ul + k * 1024),
                    16, 0, 0);
            }
        }

        #pragma unroll
        for (int j = 0; j < 8; ++j) {
            short4v p;
            p[0] = f2bf_trunc(acc[j][0]); p[1] = f2bf_trunc(acc[j][1]);
            p[2] = f2bf_trunc(acc[j][2]); p[3] = f2bf_trunc(acc[j][3]);
            *(short4v*)&Fs[fwo[j]] = p;
        }
        // same-wave RAW on LDS: only lgkmcnt needed — NO barrier
        asm volatile("s_waitcnt lgkmcnt(0)" ::: "memory");
    }
#undef T_OFK
}

// out = Cf_0 + sum_{s=1..S-1} Cb_s + sum_{s=1..S-1} log(Z_s . Y_{s-1})
//       - sum_{s=1..S-2} log sum(Y_s)
// 4 waves split the s-range (strided); deterministic LDS combine.
__global__ __launch_bounds__(256) void crf_combine(
        const float* __restrict__ yv, const float* __restrict__ zv,
        const float* __restrict__ cfv, const float* __restrict__ cbv,
        float* __restrict__ out) {
    __shared__ float part[4];
    const int b = blockIdx.x, tid = threadIdx.x;
    const int w = tid >> 6, lane = tid & 63;
    float lg = 0.f;
    for (int s = 1 + w; s <= SEG - 1; s += 4) lg += cbv[(s - 1) * NB + b];
    for (int s = 1 + w; s <= SEG - 1; s += 4) {
        const float* Z = zv + ((size_t)(s - 1) * NB + b) * NS;
        const float* Y = yv + ((size_t)(s - 1) * NB + b) * NS;
        float d = Z[lane] * Y[lane] + Z[lane + 64] * Y[lane + 64];
        #pragma unroll
        for (int off = 1; off < 64; off <<= 1) d += __shfl_xor(d, off, 64);
        lg += __logf(d);
    }
    for (int s = 1 + w; s <= SEG - 2; s += 4) {
        const float* Y = yv + ((size_t)s * NB + b) * NS;
        float t = Y[lane] + Y[lane + 64];
        #pragma unroll
        for (int off = 1; off < 64; off <<= 1) t += __shfl_xor(t, off, 64);
        lg -= __logf(t);
    }
    if (lane == 0) part[w] = lg;
    __syncthreads();
    if (tid == 0) out[b] = cfv[b] + ((part[0] + part[1]) + (part[2] + part[3]));
}

extern "C" void kernel_launch(void* const* d_in, const int* in_sizes, int n_in,
                              void* d_out, int out_size, void* d_ws, size_t ws_size,
                              hipStream_t stream) {
    const float* unary   = (const float*)d_in[0];
    const float* trans   = (const float*)d_in[1];
    const int*   lengths = (const int*)d_in[2];
    float* out = (float*)d_out;

    float* yv  = (float*)d_ws;                          // [S-1][NB][NS]
    float* zv  = yv + (size_t)(SEG - 1) * NB * NS;      // [S-1][NB][NS]
    float* cfv = zv + (size_t)(SEG - 1) * NB * NS;      // [S-1][NB]
    float* cbv = cfv + (size_t)(SEG - 1) * NB;          // [S-1][NB]

    crf_seg<<<dim3(2 * (SEG - 1) * G), dim3(64), 0, stream>>>(
        unary, trans, lengths, yv, zv, cfv, cbv);
    crf_combine<<<dim3(NB), dim3(256), 0, stream>>>(yv, zv, cfv, cbv, out);
}